// Round 10
// baseline (1261.227 us; speedup 1.0000x reference)
//
#include <hip/hip_runtime.h>

#define H 50
#define B_TOT 1024
#define S_TOT 2048

typedef float f4 __attribute__((ext_vector_type(4)));

static __device__ __forceinline__ float fast_rcp(float x) {
#if __has_builtin(__builtin_amdgcn_rcpf)
    return __builtin_amdgcn_rcpf(x);
#else
    return 1.0f / x;
#endif
}

// tanh(x) = 1 - 2/(exp(2x)+1); inf-safe at both ends.
static __device__ __forceinline__ float fast_tanh(float x) {
    return fmaf(-2.0f, fast_rcp(__expf(2.0f * x) + 1.0f), 1.0f);
}

// pp[b][j] = sum_k dps[b][k] * W_prev[j][k]
__global__ __launch_bounds__(256) void pp_kernel(const float* __restrict__ dps,
                                                 const float* __restrict__ Wp,
                                                 float* __restrict__ pp) {
    int tid = blockIdx.x * 256 + threadIdx.x;      // B*H = 51200 = 200 blocks exactly
    int b = tid / H, j = tid - b * H;
    const float* dr = dps + b * H;
    const float* wr = Wp + j * H;
    float a0 = 0.f, a1 = 0.f, a2 = 0.f, a3 = 0.f;
#pragma unroll
    for (int k = 0; k < 48; k += 4) {
        a0 = fmaf(dr[k + 0], wr[k + 0], a0);
        a1 = fmaf(dr[k + 1], wr[k + 1], a1);
        a2 = fmaf(dr[k + 2], wr[k + 2], a2);
        a3 = fmaf(dr[k + 3], wr[k + 3], a3);
    }
    a0 = fmaf(dr[48], wr[48], a0);
    a1 = fmaf(dr[49], wr[49], a1);
    pp[tid] = (a0 + a1) + (a2 + a3);
}

// WeT[k][j] = We[j][k] so the streaming k-outer loop reads contiguous rows.
__global__ __launch_bounds__(256) void wet_kernel(const float* __restrict__ We,
                                                  float* __restrict__ WeT) {
    int id = blockIdx.x * 256 + threadIdx.x;
    if (id < H * H) {
        int k = id / H, j = id - k * H;
        WeT[id] = We[j * H + k];
    }
}

// Block = 256 consecutive b's, SC consecutive s's. Per s: stage
// enc[s, b0:b0+256, :] (51200 B) into LDS with coalesced float4 loads, then
// each thread streams its own row. Score loop is k-outer with acc[25] x 2
// passes so e stays transient; WeT rows are wave-uniform -> scalar loads.
// No softmax max-subtraction: |score| <= ||W_score||_1 ~= 7, exp safe.
__global__ __launch_bounds__(256, 3) void attn_main(const float* __restrict__ enc,
                                                    const int* __restrict__ mask,
                                                    const float* __restrict__ WeT,
                                                    const float* __restrict__ Wsc,
                                                    const float* __restrict__ pp,
                                                    float* __restrict__ pl,
                                                    float* __restrict__ pctx,
                                                    int SC) {
    __shared__ float tile[256 * H];                // 51200 B -> 3 blocks/CU
    const int tid = threadIdx.x;
    const int b0 = blockIdx.y * 256;
    const int b = b0 + tid;
    const int s0 = blockIdx.x * SC;

    // ---- stage pp[b0:b0+256, :] coalesced, pull own row into registers ----
    {
        const f4* src = reinterpret_cast<const f4*>(pp + (size_t)b0 * H);
        f4* dst = reinterpret_cast<f4*>(tile);
#pragma unroll
        for (int r = 0; r < 12; ++r) dst[r * 256 + tid] = src[r * 256 + tid];
        if (tid < 128) dst[3072 + tid] = src[3072 + tid];   // waves 0,1: uniform
    }
    __syncthreads();
    float ppr[H];
#pragma unroll
    for (int q = 0; q < H; q += 2) {
        float2 v = *reinterpret_cast<const float2*>(&tile[tid * H + q]);
        ppr[q] = v.x;
        ppr[q + 1] = v.y;
    }
    __syncthreads();

    float ctx[H];
#pragma unroll
    for (int h = 0; h < H; ++h) ctx[h] = 0.f;
    float lsum = 0.f;

    const int* mrow = mask + (size_t)b * S_TOT;

#pragma unroll 1
    for (int si = 0; si < SC; ++si) {
        const int s = s0 + si;
        // ---- stage enc[s, b0:b0+256, :] (16B-aligned: (s*1024+b0)*200 B) ----
        {
            const f4* src =
                reinterpret_cast<const f4*>(enc + ((size_t)s * B_TOT + b0) * H);
            f4* dst = reinterpret_cast<f4*>(tile);
#pragma unroll
            for (int r = 0; r < 12; ++r) dst[r * 256 + tid] = src[r * 256 + tid];
            if (tid < 128) dst[3072 + tid] = src[3072 + tid];
        }
        __syncthreads();

        const float* erow = &tile[tid * H];
        float score = 0.f;
#pragma unroll
        for (int pass = 0; pass < 2; ++pass) {
            float acc[25];
#pragma unroll
            for (int jj = 0; jj < 25; ++jj) acc[jj] = ppr[pass * 25 + jj];
#pragma unroll
            for (int k = 0; k < H; k += 2) {
                float2 e2 = *reinterpret_cast<const float2*>(erow + k);
                const float* w0 = WeT + k * H + pass * 25;         // uniform
                const float* w1 = WeT + (k + 1) * H + pass * 25;   // uniform
#pragma unroll
                for (int jj = 0; jj < 25; ++jj) acc[jj] = fmaf(e2.x, w0[jj], acc[jj]);
#pragma unroll
                for (int jj = 0; jj < 25; ++jj) acc[jj] = fmaf(e2.y, w1[jj], acc[jj]);
            }
#pragma unroll
            for (int jj = 0; jj < 25; ++jj)
                score = fmaf(fast_tanh(acc[jj]), Wsc[pass * 25 + jj], score);
        }

        const float p = (mrow[s] != 0) ? __expf(score) : 0.0f;
        lsum += p;
#pragma unroll
        for (int q = 0; q < H; q += 2) {
            float2 e2 = *reinterpret_cast<const float2*>(erow + q);
            ctx[q] = fmaf(p, e2.x, ctx[q]);
            ctx[q + 1] = fmaf(p, e2.y, ctx[q + 1]);
        }
        __syncthreads();   // tile reused next si
    }

    pl[blockIdx.x * B_TOT + b] = lsum;
    float* po = pctx + ((size_t)blockIdx.x * B_TOT + b) * H;
#pragma unroll
    for (int q = 0; q < H; ++q) po[q] = ctx[q];
}

// out[b][h] = sum_c pctx[c][b][h] / sum_c pl[c][b]
__global__ __launch_bounds__(256) void combine_kernel(const float* __restrict__ pl,
                                                      const float* __restrict__ pctx,
                                                      float* __restrict__ out,
                                                      int NC) {
    int tid = blockIdx.x * 256 + threadIdx.x;      // b*H + h, coalesced over pctx
    int b = tid / H;
    float csum = 0.f, lsum = 0.f;
    for (int c = 0; c < NC; ++c) {
        csum += pctx[(size_t)c * (B_TOT * H) + tid];
        lsum += pl[c * B_TOT + b];
    }
    out[tid] = csum / lsum;
}

extern "C" void kernel_launch(void* const* d_in, const int* in_sizes, int n_in,
                              void* d_out, int out_size, void* d_ws, size_t ws_size,
                              hipStream_t stream) {
    const float* dps  = (const float*)d_in[0];
    const float* enc  = (const float*)d_in[1];
    const int*   mask = (const int*)d_in[2];
    const float* Wp   = (const float*)d_in[3];
    const float* We   = (const float*)d_in[4];
    const float* Wsc  = (const float*)d_in[5];
    float* out = (float*)d_out;
    float* ws  = (float*)d_ws;

    // ws layout: pp | pl | pctx | WeT. Halve NC until it fits.
    int NC = 256;
    while (NC > 1 &&
           (size_t)(B_TOT * H + (size_t)NC * B_TOT * (H + 1) + H * H) * sizeof(float) >
               ws_size)
        NC >>= 1;
    const int SC = S_TOT / NC;

    float* pp   = ws;
    float* pl   = ws + B_TOT * H;
    float* pctx = pl + (size_t)NC * B_TOT;
    float* WeT  = pctx + (size_t)NC * B_TOT * H;

    hipLaunchKernelGGL(pp_kernel, dim3((B_TOT * H) / 256), dim3(256), 0, stream,
                       dps, Wp, pp);
    hipLaunchKernelGGL(wet_kernel, dim3((H * H + 255) / 256), dim3(256), 0, stream,
                       We, WeT);
    hipLaunchKernelGGL(attn_main, dim3(NC, B_TOT / 256), dim3(256), 0, stream,
                       enc, mask, WeT, Wsc, pp, pl, pctx, SC);
    hipLaunchKernelGGL(combine_kernel, dim3((B_TOT * H) / 256), dim3(256), 0, stream,
                       pl, pctx, out, NC);
}